// Round 11
// baseline (196.807 us; speedup 1.0000x reference)
//
#include <hip/hip_runtime.h>

typedef unsigned short u16;
typedef unsigned int u32;

#define LL 512
#define DIMC 64
#define HIDC 128

typedef __attribute__((ext_vector_type(8))) __bf16 bf16x8;
typedef __attribute__((ext_vector_type(4))) float f32x4;

__device__ __forceinline__ u16 f2bf(float f) {
  u32 u = __float_as_uint(f);
  u = u + 0x7FFFu + ((u >> 16) & 1u);   // RNE
  return (u16)(u >> 16);
}
__device__ __forceinline__ float bf2f(u32 us) {
  return __uint_as_float(us << 16);
}
__device__ __forceinline__ float sigm(float x) {
  return 1.0f / (1.0f + __expf(-x));
}

// ================= EMPIRICAL LAW (r5-r9) =================
// MFMA B-operands MUST be consumed from LDS-staged swizzled images.
// - LDS-staged B (r2/r3/r4/r8/r10): PASS, deterministic across replays.
// - Global-consumed B (r5/r6/r7 reg-frags; r9 direct global reads at the
//   SAME byte offsets): FAIL — elevated absmax + post-timing drift.
// Do not re-litigate without new evidence.
// =========================================================

// ---- prep: build swizzled bf16 weight images (r8 verbatim) --------------
extern "C" __global__ void prep(const float* __restrict__ Wr, const float* __restrict__ Wrg,
                                const float* __restrict__ Wog, const float* __restrict__ Wl,
                                const float* __restrict__ Wlg, const float* __restrict__ Wo,
                                u16* __restrict__ WTr, u16* __restrict__ WTl,
                                u16* __restrict__ WoT)
{
  int t = blockIdx.x * blockDim.x + threadIdx.x;
  int stride = gridDim.x * blockDim.x;
  for (int idx = t; idx < 384 * 64; idx += stride) {
    int n = idx >> 6, k = idx & 63;
    const float* W = (n < 128) ? Wr : (n < 256 ? Wrg : Wog);
    WTr[(n << 6) + (((k >> 3) ^ (n & 7)) << 3) + (k & 7)] = f2bf(W[k * HIDC + (n & 127)]);
  }
  for (int idx = t; idx < 256 * 64; idx += stride) {
    int n = idx >> 6, k = idx & 63;
    const float* W = (n < 128) ? Wl : Wlg;
    WTl[(n << 6) + (((k >> 3) ^ (n & 7)) << 3) + (k & 7)] = f2bf(W[k * HIDC + (n & 127)]);
  }
  for (int idx = t; idx < 64 * 128; idx += stride) {
    int d = idx >> 7, k = idx & 127;
    WoT[(d << 7) + (((k >> 3) ^ (d & 7)) << 3) + (k & 7)] = f2bf(Wo[k * DIMC + d]);
  }
}

// ---- kernel Ring: LN + right projection (r10 verbatim, bounds 3->4) -----
// LDS exactly 40KB (32KB sWT + 8KB sA) -> 4 blocks/CU.
extern "C" __global__ void __launch_bounds__(256, 4)
kernRing(const float* __restrict__ x, const int* __restrict__ smask,
         const float* __restrict__ ns, const float* __restrict__ nb,
         const float* __restrict__ br, const float* __restrict__ brg,
         const u16* __restrict__ WTr, u16* __restrict__ ring, int k0)
{
  __shared__ u16 sWT[256 * 64];   // 32KB, swizzled image rows 0..255
  __shared__ u16 sA[64 * 64];     // 8KB, swizzled
  const int bid = blockIdx.x;
  const int slot = bid >> 3, tile = bid & 7;
  const int p = k0 + slot;
  if (p < 0 || p >= LL) return;
  const int t = threadIdx.x;
  const int lane = t & 63;
  const int wave = t >> 6;
  const int l15 = lane & 15, l4 = lane >> 4;
  const int q0 = tile * 64;

  { // stage Wr|Wrg: linear uint4 copy of pre-swizzled image
    const uint4* src = (const uint4*)WTr;
    uint4* dst = (uint4*)sWT;
#pragma unroll
    for (int c = 0; c < 8; ++c) dst[t + c * 256] = src[t + c * 256];
  }

  const float mrow = (float)smask[p];
  const int ql = t >> 2, qc = t & 3;      // pair-in-tile, dim-quarter
  float4 nsv[4], nbv[4];
#pragma unroll
  for (int j = 0; j < 4; j++) {
    nsv[j] = *(const float4*)(ns + qc * 16 + j * 4);
    nbv[j] = *(const float4*)(nb + qc * 16 + j * 4);
  }
  float brv[2], brgv[2];
#pragma unroll
  for (int fp = 0; fp < 2; fp++) {
    int h = wave * 32 + fp * 16 + l15;
    brv[fp] = br[h]; brgv[fp] = brg[h];
  }

  { // ---- LN -> sA (bf16, swizzled) — verified verbatim
    const int q = q0 + ql;
    const float* xp = x + ((size_t)p * LL + q) * DIMC + qc * 16;
    float4 xv[4];
    float s = 0.f, ss = 0.f;
#pragma unroll
    for (int j = 0; j < 4; j++) {
      xv[j] = *(const float4*)(xp + j * 4);
      s += xv[j].x + xv[j].y + xv[j].z + xv[j].w;
      ss += xv[j].x * xv[j].x + xv[j].y * xv[j].y + xv[j].z * xv[j].z + xv[j].w * xv[j].w;
    }
    s += __shfl_xor(s, 1); ss += __shfl_xor(ss, 1);
    s += __shfl_xor(s, 2); ss += __shfl_xor(ss, 2);
    const float mean = s * (1.f / 64.f);
    const float var = ss * (1.f / 64.f) - mean * mean;
    const float rstd = rsqrtf(var + 1e-6f);
    u16 xb[16];
#pragma unroll
    for (int j = 0; j < 4; j++) {
      xb[j*4+0] = f2bf((xv[j].x - mean) * rstd * nsv[j].x + nbv[j].x);
      xb[j*4+1] = f2bf((xv[j].y - mean) * rstd * nsv[j].y + nbv[j].y);
      xb[j*4+2] = f2bf((xv[j].z - mean) * rstd * nsv[j].z + nbv[j].z);
      xb[j*4+3] = f2bf((xv[j].w - mean) * rstd * nsv[j].w + nbv[j].w);
    }
    uint4 c0, c1;
    c0.x = (u32)xb[0]  | ((u32)xb[1]  << 16);
    c0.y = (u32)xb[2]  | ((u32)xb[3]  << 16);
    c0.z = (u32)xb[4]  | ((u32)xb[5]  << 16);
    c0.w = (u32)xb[6]  | ((u32)xb[7]  << 16);
    c1.x = (u32)xb[8]  | ((u32)xb[9]  << 16);
    c1.y = (u32)xb[10] | ((u32)xb[11] << 16);
    c1.z = (u32)xb[12] | ((u32)xb[13] << 16);
    c1.w = (u32)xb[14] | ((u32)xb[15] << 16);
    char* rowp = (char*)sA + ql * 128;
    *(uint4*)(rowp + (((qc * 2 + 0) ^ (ql & 7)) << 4)) = c0;
    *(uint4*)(rowp + (((qc * 2 + 1) ^ (ql & 7)) << 4)) = c1;
  }
  __syncthreads();
  // ---- MFMA: [64 pairs x 64k] @ [64k x 256n] (Wr|Wrg groups)
  f32x4 acc[4][4];
  f32x4 zero = {0.f, 0.f, 0.f, 0.f};
#pragma unroll
  for (int m = 0; m < 4; m++)
#pragma unroll
    for (int f = 0; f < 4; f++) acc[m][f] = zero;
#pragma unroll
  for (int ks = 0; ks < 2; ks++) {
    bf16x8 av[4];
#pragma unroll
    for (int m = 0; m < 4; m++) {
      int row = m * 16 + l15;
      int ch = (ks * 4 + l4) ^ (row & 7);
      av[m] = *(const bf16x8*)((const char*)sA + row * 128 + (ch << 4));
    }
#pragma unroll
    for (int f = 0; f < 4; f++) {
      int g = f >> 1, fp = f & 1;
      int n = g * 128 + wave * 32 + fp * 16 + l15;
      int ch = (ks * 4 + l4) ^ (n & 7);
      bf16x8 bv = *(const bf16x8*)((const char*)sWT + n * 128 + (ch << 4));
#pragma unroll
      for (int m = 0; m < 4; m++)
        acc[m][f] = __builtin_amdgcn_mfma_f32_16x16x32_bf16(av[m], bv, acc[m][f], 0, 0, 0);
    }
  }
  // ---- epilogue: bias, mask, sigmoid gate; scalar ring stores
#pragma unroll
  for (int m = 0; m < 4; m++) {
    float mvr[4];
#pragma unroll
    for (int r = 0; r < 4; r++)
      mvr[r] = mrow * (float)smask[q0 + m * 16 + l4 * 4 + r];
#pragma unroll
    for (int fp = 0; fp < 2; fp++) {
      const int h = wave * 32 + fp * 16 + l15;
      f32x4 lin = acc[m][fp];
      f32x4 gat = acc[m][2 + fp];
#pragma unroll
      for (int r = 0; r < 4; r++) {
        const int qq = q0 + m * 16 + l4 * 4 + r;
        ring[((size_t)slot * LL + qq) * HIDC + h] =
            f2bf((lin[r] + brv[fp]) * mvr[r] * sigm(gat[r] + brgv[fp]));
      }
    }
  }
}

// ---- kernel Og: LN + out-gate projection (r10 verbatim) -----------------
extern "C" __global__ void __launch_bounds__(256, 4)
kernOg(const float* __restrict__ x, const int* __restrict__ smask,
       const float* __restrict__ ns, const float* __restrict__ nb,
       const float* __restrict__ bog, const u16* __restrict__ WTr,
       u16* __restrict__ og, int i0)
{
  __shared__ u16 sWog[128 * 64];  // 16KB, swizzled image rows 256..383
  __shared__ u16 sA[64 * 64];     // 8KB, swizzled
  const int bid = blockIdx.x;
  const int p = i0 + (bid >> 3);
  const int tile = bid & 7;
  const int t = threadIdx.x;
  const int lane = t & 63;
  const int wave = t >> 6;
  const int l15 = lane & 15, l4 = lane >> 4;
  const int q0 = tile * 64;

  { // stage Wog: linear uint4 copy of image rows 256..383
    const uint4* src = (const uint4*)(WTr + 256 * 64);
    uint4* dst = (uint4*)sWog;
#pragma unroll
    for (int c = 0; c < 4; ++c) dst[t + c * 256] = src[t + c * 256];
  }

  const int ql = t >> 2, qc = t & 3;      // pair-in-tile, dim-quarter
  float4 nsv[4], nbv[4];
#pragma unroll
  for (int j = 0; j < 4; j++) {
    nsv[j] = *(const float4*)(ns + qc * 16 + j * 4);
    nbv[j] = *(const float4*)(nb + qc * 16 + j * 4);
  }
  float bogv[2];
#pragma unroll
  for (int fp = 0; fp < 2; fp++) bogv[fp] = bog[wave * 32 + fp * 16 + l15];

  { // ---- LN -> sA (bf16, swizzled) — verified verbatim
    const int q = q0 + ql;
    const float* xp = x + ((size_t)p * LL + q) * DIMC + qc * 16;
    float4 xv[4];
    float s = 0.f, ss = 0.f;
#pragma unroll
    for (int j = 0; j < 4; j++) {
      xv[j] = *(const float4*)(xp + j * 4);
      s += xv[j].x + xv[j].y + xv[j].z + xv[j].w;
      ss += xv[j].x * xv[j].x + xv[j].y * xv[j].y + xv[j].z * xv[j].z + xv[j].w * xv[j].w;
    }
    s += __shfl_xor(s, 1); ss += __shfl_xor(ss, 1);
    s += __shfl_xor(s, 2); ss += __shfl_xor(ss, 2);
    const float mean = s * (1.f / 64.f);
    const float rstd = rsqrtf(ss * (1.f / 64.f) - mean * mean + 1e-6f);
    u16 xb[16];
#pragma unroll
    for (int j = 0; j < 4; j++) {
      xb[j*4+0] = f2bf((xv[j].x - mean) * rstd * nsv[j].x + nbv[j].x);
      xb[j*4+1] = f2bf((xv[j].y - mean) * rstd * nsv[j].y + nbv[j].y);
      xb[j*4+2] = f2bf((xv[j].z - mean) * rstd * nsv[j].z + nbv[j].z);
      xb[j*4+3] = f2bf((xv[j].w - mean) * rstd * nsv[j].w + nbv[j].w);
    }
    uint4 c0, c1;
    c0.x = (u32)xb[0]  | ((u32)xb[1]  << 16);
    c0.y = (u32)xb[2]  | ((u32)xb[3]  << 16);
    c0.z = (u32)xb[4]  | ((u32)xb[5]  << 16);
    c0.w = (u32)xb[6]  | ((u32)xb[7]  << 16);
    c1.x = (u32)xb[8]  | ((u32)xb[9]  << 16);
    c1.y = (u32)xb[10] | ((u32)xb[11] << 16);
    c1.z = (u32)xb[12] | ((u32)xb[13] << 16);
    c1.w = (u32)xb[14] | ((u32)xb[15] << 16);
    char* rowp = (char*)sA + ql * 128;
    *(uint4*)(rowp + (((qc * 2 + 0) ^ (ql & 7)) << 4)) = c0;
    *(uint4*)(rowp + (((qc * 2 + 1) ^ (ql & 7)) << 4)) = c1;
  }
  __syncthreads();
  // ---- MFMA: [64 pairs x 64k] @ [64k x 128n] (Wog group)
  f32x4 acc[4][2];
  f32x4 zero = {0.f, 0.f, 0.f, 0.f};
#pragma unroll
  for (int m = 0; m < 4; m++) { acc[m][0] = zero; acc[m][1] = zero; }
#pragma unroll
  for (int ks = 0; ks < 2; ks++) {
    bf16x8 av[4];
#pragma unroll
    for (int m = 0; m < 4; m++) {
      int row = m * 16 + l15;
      int ch = (ks * 4 + l4) ^ (row & 7);
      av[m] = *(const bf16x8*)((const char*)sA + row * 128 + (ch << 4));
    }
#pragma unroll
    for (int fp = 0; fp < 2; fp++) {
      int n = wave * 32 + fp * 16 + l15;       // image row 256+n; (256+n)&7 == n&7
      int ch = (ks * 4 + l4) ^ (n & 7);
      bf16x8 bv = *(const bf16x8*)((const char*)sWog + n * 128 + (ch << 4));
#pragma unroll
      for (int m = 0; m < 4; m++)
        acc[m][fp] = __builtin_amdgcn_mfma_f32_16x16x32_bf16(av[m], bv, acc[m][fp], 0, 0, 0);
    }
  }
  // ---- epilogue: sigmoid; scalar og stores
#pragma unroll
  for (int m = 0; m < 4; m++)
#pragma unroll
    for (int fp = 0; fp < 2; fp++) {
      const int h = wave * 32 + fp * 16 + l15;
      f32x4 ogv = acc[m][fp];
#pragma unroll
      for (int r = 0; r < 4; r++) {
        const int qq = q0 + m * 16 + l4 * 4 + r;
        og[((size_t)p * LL + qq) * HIDC + h] = f2bf(sigm(ogv[r] + bogv[fp]));
      }
    }
}

// ---- kernel L: left on the 9 diagonals via MFMA (r10 verbatim) ----------
extern "C" __global__ void __launch_bounds__(256, 2)
kernL(const float* __restrict__ x, const int* __restrict__ smask,
      const float* __restrict__ ns, const float* __restrict__ nb,
      const float* __restrict__ bl, const float* __restrict__ blg,
      const u16* __restrict__ WTl, float* __restrict__ Lbuf)
{
  __shared__ u16 sW[256 * 64];    // 32KB swizzled image
  __shared__ u16 sA[64 * 64];     // 8KB swizzled LN'd rows
  const int g0 = blockIdx.x * 64;
  const int t = threadIdx.x;
  const int lane = t & 63, wave = t >> 6;
  const int l15 = lane & 15, l4 = lane >> 4;

  { // stage weights: linear uint4 copy of pre-swizzled image
    const uint4* src = (const uint4*)WTl;
    uint4* dst = (uint4*)sW;
#pragma unroll
    for (int c = 0; c < 8; ++c) dst[t + c * 256] = src[t + c * 256];
  }

  const int ql = t >> 2, qc = t & 3;     // row-in-tile, dim-quarter
  { // ---- LN -> sA: row g = g0+ql -> (i = g/9, d = g%9, p = i+d-4)
    const int g = g0 + ql;
    const int i = g / 9, d = g - 9 * i;
    int p = i + d - 4;
    p = (p < 0) ? 0 : (p > LL - 1 ? LL - 1 : p);   // clamp; invalid rows zeroed later
    const float* xp = x + ((size_t)p * LL + i) * DIMC + qc * 16;
    float4 xv[4];
    float s = 0.f, ss = 0.f;
#pragma unroll
    for (int j = 0; j < 4; j++) {
      xv[j] = *(const float4*)(xp + j * 4);
      s += xv[j].x + xv[j].y + xv[j].z + xv[j].w;
      ss += xv[j].x * xv[j].x + xv[j].y * xv[j].y + xv[j].z * xv[j].z + xv[j].w * xv[j].w;
    }
    s += __shfl_xor(s, 1); ss += __shfl_xor(ss, 1);
    s += __shfl_xor(s, 2); ss += __shfl_xor(ss, 2);
    const float mean = s * (1.f / 64.f);
    const float rstd = rsqrtf(ss * (1.f / 64.f) - mean * mean + 1e-6f);
    u16 xb[16];
#pragma unroll
    for (int j = 0; j < 4; j++) {
      const float4 nsv = *(const float4*)(ns + qc * 16 + j * 4);
      const float4 nbv = *(const float4*)(nb + qc * 16 + j * 4);
      xb[j*4+0] = f2bf((xv[j].x - mean) * rstd * nsv.x + nbv.x);
      xb[j*4+1] = f2bf((xv[j].y - mean) * rstd * nsv.y + nbv.y);
      xb[j*4+2] = f2bf((xv[j].z - mean) * rstd * nsv.z + nbv.z);
      xb[j*4+3] = f2bf((xv[j].w - mean) * rstd * nsv.w + nbv.w);
    }
    uint4 c0, c1;
    c0.x = (u32)xb[0]  | ((u32)xb[1]  << 16);
    c0.y = (u32)xb[2]  | ((u32)xb[3]  << 16);
    c0.z = (u32)xb[4]  | ((u32)xb[5]  << 16);
    c0.w = (u32)xb[6]  | ((u32)xb[7]  << 16);
    c1.x = (u32)xb[8]  | ((u32)xb[9]  << 16);
    c1.y = (u32)xb[10] | ((u32)xb[11] << 16);
    c1.z = (u32)xb[12] | ((u32)xb[13] << 16);
    c1.w = (u32)xb[14] | ((u32)xb[15] << 16);
    char* rowp = (char*)sA + ql * 128;
    *(uint4*)(rowp + (((qc * 2 + 0) ^ (ql & 7)) << 4)) = c0;
    *(uint4*)(rowp + (((qc * 2 + 1) ^ (ql & 7)) << 4)) = c1;
  }
  __syncthreads();
  // ---- MFMA: [64 rows x 64k] @ [64k x 256n]
  f32x4 acc[4][4];
  f32x4 zero = {0.f, 0.f, 0.f, 0.f};
#pragma unroll
  for (int m = 0; m < 4; m++)
#pragma unroll
    for (int f = 0; f < 4; f++) acc[m][f] = zero;
#pragma unroll
  for (int ks = 0; ks < 2; ks++) {
    bf16x8 av[4];
#pragma unroll
    for (int m = 0; m < 4; m++) {
      int row = m * 16 + l15;
      int ch = (ks * 4 + l4) ^ (row & 7);
      av[m] = *(const bf16x8*)((const char*)sA + row * 128 + (ch << 4));
    }
#pragma unroll
    for (int f = 0; f < 4; f++) {
      int grp = f >> 1, fp = f & 1;
      int n = grp * 128 + wave * 32 + fp * 16 + l15;
      int ch = (ks * 4 + l4) ^ (n & 7);
      bf16x8 bv = *(const bf16x8*)((const char*)sW + n * 128 + (ch << 4));
#pragma unroll
      for (int m = 0; m < 4; m++)
        acc[m][f] = __builtin_amdgcn_mfma_f32_16x16x32_bf16(av[m], bv, acc[m][f], 0, 0, 0);
    }
  }
  // ---- epilogue: (lin+bl)*mask*sigm(gate+blg) -> Lbuf f32
  // NOTE: invalid diagonals (p outside [0,LL)) write EXACT 0 — kernB's
  // unconditional 9-d pipeline relies on this.
#pragma unroll
  for (int fp = 0; fp < 2; fp++) {
    const int h = wave * 32 + fp * 16 + l15;
    const float blv = bl[h], blgv = blg[h];
#pragma unroll
    for (int m = 0; m < 4; m++) {
      f32x4 lin = acc[m][fp];
      f32x4 gat = acc[m][2 + fp];
#pragma unroll
      for (int r = 0; r < 4; r++) {
        const int g = g0 + m * 16 + l4 * 4 + r;
        const int i = g / 9, d = g - 9 * i;
        const int p = i + d - 4;
        const bool valid = (p >= 0) && (p < LL);
        const float mv = valid ? (float)smask[i] * (float)smask[valid ? p : 0] : 0.f;
        Lbuf[(size_t)g * HIDC + h] = (lin[r] + blv) * mv * sigm(gat[r] + blgv);
      }
    }
  }
}

// ---- kernel B: banded product + LN + gate + Wo projection ---------------
// r11 changes (values identical):
//  * sLb quarter-rotated layout kills the 4-way bank conflict (3.27M cyc):
//    float e of quarter q stored at q*32 + ((e + q*8)&31).
//  * unconditional 9-d ring pipeline, 3-buffer prefetch (12 uint4 in
//    flight). Slot si+d always in-ring; invalid rows have sLb == 0 and all
//    ring bytes are finite bf16, so fmaf(0,x,acc)==acc exactly.
//  * first 3 load batches issued before the staging barrier; og prefetched
//    before the LN reduction.
extern "C" __global__ void __launch_bounds__(256, 4)
kernB(const u16* __restrict__ ring, const u16* og,
      const float* __restrict__ Lbuf, const u16* __restrict__ WoT,
      const float* __restrict__ osc, const float* __restrict__ obi,
      const float* __restrict__ bo, float* out, int k0, int i0)
{
  __shared__ u16 sWo[64 * 128];   // 16KB swizzled image
  __shared__ u16 sA[64 * 128];    // 16KB swizzled product tile
  __shared__ float sLb[9 * 128];  // 4.6KB, quarter-rotated
  const int bid = blockIdx.x;
  const int i = i0 + (bid >> 3), j0 = (bid & 7) * 64;
  const int t = threadIdx.x;
  const int lane = t & 63, wave = t >> 6;
  const int l15 = lane & 15, l4 = lane >> 4;
  const int j = t >> 2, hq = t & 3, h0 = hq * 32;
  const int si = i - i0;                    // ring slot of d=0 (= (i-4)-k0)
  const size_t jrow = (size_t)(j0 + j);

  // ---- ring prefetch pipeline buffers; issue first 3 batches now
  uint4 rv[3][4];
#define RLOAD(dv, b) { const uint4* rp = (const uint4*)(ring + \
      ((size_t)(si + (dv)) * LL + jrow) * HIDC + h0); \
    rv[b][0] = rp[0]; rv[b][1] = rp[1]; rv[b][2] = rp[2]; rv[b][3] = rp[3]; }
  RLOAD(0, 0); RLOAD(1, 1); RLOAD(2, 2);

  { // stage Wo image + rotated sLb
    const uint4* src = (const uint4*)WoT;
    uint4* dst = (uint4*)sWo;
#pragma unroll
    for (int c = 0; c < 4; ++c) dst[t + c * 256] = src[t + c * 256];
    const float* lb = Lbuf + (size_t)i * (9 * HIDC);
    for (int idx = t; idx < 9 * HIDC; idx += 256) {
      const int d = idx >> 7, r = idx & 127, q = r >> 5, e = r & 31;
      sLb[d * 128 + q * 32 + ((e + q * 8) & 31)] = lb[idx];
    }
  }
  __syncthreads();

  float acc[32];
#pragma unroll
  for (int e = 0; e < 32; e++) acc[e] = 0.f;
#pragma unroll
  for (int d = 0; d < 9; d++) {
#pragma unroll
    for (int c4 = 0; c4 < 4; c4++) {
      const uint4 rvv = rv[d % 3][c4];
      const int e0 = (c4 * 8 + hq * 8) & 31;
      const int e1 = (c4 * 8 + 4 + hq * 8) & 31;
      const float4 lb0 = *(const float4*)(sLb + d * 128 + hq * 32 + e0);
      const float4 lb1 = *(const float4*)(sLb + d * 128 + hq * 32 + e1);
      acc[c4*8+0] = fmaf(lb0.x, bf2f(rvv.x & 0xffff), acc[c4*8+0]);
      acc[c4*8+1] = fmaf(lb0.y, bf2f(rvv.x >> 16),    acc[c4*8+1]);
      acc[c4*8+2] = fmaf(lb0.z, bf2f(rvv.y & 0xffff), acc[c4*8+2]);
      acc[c4*8+3] = fmaf(lb0.w, bf2f(rvv.y >> 16),    acc[c4*8+3]);
      acc[c4*8+4] = fmaf(lb1.x, bf2f(rvv.z & 0xffff), acc[c4*8+4]);
      acc[c4*8+5] = fmaf(lb1.y, bf2f(rvv.z >> 16),    acc[c4*8+5]);
      acc[c4*8+6] = fmaf(lb1.z, bf2f(rvv.w & 0xffff), acc[c4*8+6]);
      acc[c4*8+7] = fmaf(lb1.w, bf2f(rvv.w >> 16),    acc[c4*8+7]);
    }
    if (d + 3 < 9) { RLOAD(d + 3, d % 3); }
  }
#undef RLOAD

  // ---- prefetch og tile (covers LN reduction latency)
  uint4 gvv[4];
  {
    const uint4* ogp = (const uint4*)(og + ((size_t)i * LL + jrow) * HIDC + h0);
#pragma unroll
    for (int c4 = 0; c4 < 4; c4++) gvv[c4] = ogp[c4];
  }

  // LN over 128 (4 threads per j)
  float s = 0.f, ss = 0.f;
#pragma unroll
  for (int e = 0; e < 32; e++) { s += acc[e]; ss += acc[e] * acc[e]; }
  s += __shfl_xor(s, 1); ss += __shfl_xor(ss, 1);
  s += __shfl_xor(s, 2); ss += __shfl_xor(ss, 2);
  const float mean = s * (1.f / 128.f);
  const float rstd = rsqrtf(ss * (1.f / 128.f) - mean * mean + 1e-6f);
  char* rowp = (char*)sA + j * 256;
#pragma unroll
  for (int c4 = 0; c4 < 4; c4++) {
    const float4 o0 = *(const float4*)(osc + h0 + c4 * 8);
    const float4 o1 = *(const float4*)(osc + h0 + c4 * 8 + 4);
    const float4 b0 = *(const float4*)(obi + h0 + c4 * 8);
    const float4 b1 = *(const float4*)(obi + h0 + c4 * 8 + 4);
    const uint4 gv = gvv[c4];
    float v0 = ((acc[c4*8+0] - mean) * rstd * o0.x + b0.x) * bf2f(gv.x & 0xffff);
    float v1 = ((acc[c4*8+1] - mean) * rstd * o0.y + b0.y) * bf2f(gv.x >> 16);
    float v2 = ((acc[c4*8+2] - mean) * rstd * o0.z + b0.z) * bf2f(gv.y & 0xffff);
    float v3 = ((acc[c4*8+3] - mean) * rstd * o0.w + b0.w) * bf2f(gv.y >> 16);
    float v4 = ((acc[c4*8+4] - mean) * rstd * o1.x + b1.x) * bf2f(gv.z & 0xffff);
    float v5 = ((acc[c4*8+5] - mean) * rstd * o1.y + b1.y) * bf2f(gv.z >> 16);
    float v6 = ((acc[c4*8+6] - mean) * rstd * o1.z + b1.z) * bf2f(gv.w & 0xffff);
    float v7 = ((acc[c4*8+7] - mean) * rstd * o1.w + b1.w) * bf2f(gv.w >> 16);
    uint4 pk;
    pk.x = (u32)f2bf(v0) | ((u32)f2bf(v1) << 16);
    pk.y = (u32)f2bf(v2) | ((u32)f2bf(v3) << 16);
    pk.z = (u32)f2bf(v4) | ((u32)f2bf(v5) << 16);
    pk.w = (u32)f2bf(v6) | ((u32)f2bf(v7) << 16);
    *(uint4*)(rowp + (((hq * 4 + c4) ^ (j & 7)) << 4)) = pk;
  }
  __syncthreads();   // og fully read; sA ready
  f32x4 acc2[4];
  f32x4 zero = {0.f, 0.f, 0.f, 0.f};
#pragma unroll
  for (int m = 0; m < 4; m++) acc2[m] = zero;
#pragma unroll
  for (int ks = 0; ks < 4; ks++) {
    int n = wave * 16 + l15;
    int chb = (ks * 4 + l4) ^ (n & 7);
    bf16x8 bv = *(const bf16x8*)((const char*)sWo + n * 256 + (chb << 4));
#pragma unroll
    for (int m = 0; m < 4; m++) {
      int row = m * 16 + l15;
      int cha = (ks * 4 + l4) ^ (row & 7);
      bf16x8 av = *(const bf16x8*)((const char*)sA + row * 256 + (cha << 4));
      acc2[m] = __builtin_amdgcn_mfma_f32_16x16x32_bf16(av, bv, acc2[m], 0, 0, 0);
    }
  }
  const int dim = wave * 16 + l15;
  const float bov = bo[dim];
#pragma unroll
  for (int m = 0; m < 4; m++) {
#pragma unroll
    for (int r = 0; r < 4; r++) {
      int jj = j0 + m * 16 + l4 * 4 + r;
      out[((size_t)i * LL + jj) * DIMC + dim] = acc2[m][r] + bov;
    }
  }
}

extern "C" void kernel_launch(void* const* d_in, const int* in_sizes, int n_in,
                              void* d_out, int out_size, void* d_ws, size_t ws_size,
                              hipStream_t stream) {
  const float* x    = (const float*)d_in[0];
  const int*   sm   = (const int*)d_in[1];
  const float* ns   = (const float*)d_in[2];
  const float* nb   = (const float*)d_in[3];
  const float* Wl   = (const float*)d_in[4];
  const float* bl   = (const float*)d_in[5];
  const float* Wr   = (const float*)d_in[6];
  const float* br   = (const float*)d_in[7];
  const float* Wlg  = (const float*)d_in[8];
  const float* blg  = (const float*)d_in[9];
  const float* Wrg  = (const float*)d_in[10];
  const float* brg  = (const float*)d_in[11];
  const float* Wog  = (const float*)d_in[12];
  const float* bog  = (const float*)d_in[13];
  const float* osc  = (const float*)d_in[14];
  const float* obi  = (const float*)d_in[15];
  const float* Wo   = (const float*)d_in[16];
  const float* bo   = (const float*)d_in[17];

  // ws layout: Lbuf f32 | WTr 48KB | WTl 32KB | WoT 16KB | ring.
  const size_t LBUF_BYTES = (size_t)LL * 9 * HIDC * 4;   // 2,359,296
  char* ws = (char*)d_ws;
  float* Lbuf = (float*)ws;
  u16* WTr = (u16*)(ws + LBUF_BYTES);
  u16* WTl = (u16*)(ws + LBUF_BYTES + 49152);
  u16* WoT = (u16*)(ws + LBUF_BYTES + 49152 + 32768);
  u16* ring = (u16*)(ws + LBUF_BYTES + 49152 + 32768 + 16384);

  int CHUNK = 256;
  if (ws_size < LBUF_BYTES + 98304 + (size_t)(256 + 8) * LL * HIDC * 2) CHUNK = 64;
  u16* ogB = (u16*)d_out;   // og lives in d_out, chunk-local, consumed by kernB

  prep<<<32, 256, 0, stream>>>(Wr, Wrg, Wog, Wl, Wlg, Wo, WTr, WTl, WoT);
  kernL<<<72, 256, 0, stream>>>(x, sm, ns, nb, bl, blg, WTl, Lbuf);
  for (int i0 = 0; i0 < LL; i0 += CHUNK) {
    const int k0 = i0 - 4;
    kernRing<<<(CHUNK + 8) * 8, 256, 0, stream>>>(x, sm, ns, nb, br, brg, WTr, ring, k0);
    kernOg<<<CHUNK * 8, 256, 0, stream>>>(x, sm, ns, nb, bog, WTr, ogB, i0);
    kernB<<<CHUNK * 8, 256, 0, stream>>>(ring, ogB, Lbuf, WoT, osc, obi, bo,
                                         (float*)d_out, k0, i0);
  }
}

// Round 12
// 183.224 us; speedup vs baseline: 1.0741x; 1.0741x over previous
//
#include <hip/hip_runtime.h>

typedef unsigned short u16;
typedef unsigned int u32;

#define LL 512
#define DIMC 64
#define HIDC 128

typedef __attribute__((ext_vector_type(8))) __bf16 bf16x8;
typedef __attribute__((ext_vector_type(4))) float f32x4;

__device__ __forceinline__ u16 f2bf(float f) {
  u32 u = __float_as_uint(f);
  u = u + 0x7FFFu + ((u >> 16) & 1u);   // RNE
  return (u16)(u >> 16);
}
__device__ __forceinline__ float bf2f(u32 us) {
  return __uint_as_float(us << 16);
}
__device__ __forceinline__ float sigm(float x) {
  return 1.0f / (1.0f + __expf(-x));
}

// ================= EMPIRICAL LAWS =================
// LAW 1 (r5-r9): MFMA B-operands MUST be consumed from LDS-staged swizzled
// images. Global-consumed B (reg-frags or direct reads at identical byte
// offsets) => elevated absmax + post-timing drift. Do not re-litigate.
// LAW 2 (r4/r8 vs r10/r11): kernB's speed is set by producer->consumer
// launch adjacency. ring (33.8MB) must be written by the IMMEDIATELY
// preceding launch or it falls out of L2 (18us -> 48us). Hence per-chunk
// order: kernOg, kernRing, kernB.
// LAW 3 (r11): kernB "optimizations" (sLb rotation, manual 3-deep ring
// prefetch) regressed 48->58us; bank conflicts were 1600 cyc/block = noise.
// r10 kernB source is the verified-fast form given adjacency.
// ==================================================

// ---- prep: build swizzled bf16 weight images (r8 verbatim) --------------
extern "C" __global__ void prep(const float* __restrict__ Wr, const float* __restrict__ Wrg,
                                const float* __restrict__ Wog, const float* __restrict__ Wl,
                                const float* __restrict__ Wlg, const float* __restrict__ Wo,
                                u16* __restrict__ WTr, u16* __restrict__ WTl,
                                u16* __restrict__ WoT)
{
  int t = blockIdx.x * blockDim.x + threadIdx.x;
  int stride = gridDim.x * blockDim.x;
  for (int idx = t; idx < 384 * 64; idx += stride) {
    int n = idx >> 6, k = idx & 63;
    const float* W = (n < 128) ? Wr : (n < 256 ? Wrg : Wog);
    WTr[(n << 6) + (((k >> 3) ^ (n & 7)) << 3) + (k & 7)] = f2bf(W[k * HIDC + (n & 127)]);
  }
  for (int idx = t; idx < 256 * 64; idx += stride) {
    int n = idx >> 6, k = idx & 63;
    const float* W = (n < 128) ? Wl : Wlg;
    WTl[(n << 6) + (((k >> 3) ^ (n & 7)) << 3) + (k & 7)] = f2bf(W[k * HIDC + (n & 127)]);
  }
  for (int idx = t; idx < 64 * 128; idx += stride) {
    int d = idx >> 7, k = idx & 127;
    WoT[(d << 7) + (((k >> 3) ^ (d & 7)) << 3) + (k & 7)] = f2bf(Wo[k * DIMC + d]);
  }
}

// ---- kernel Ring: LN + right projection (LDS 40KB -> 4 blocks/CU) -------
extern "C" __global__ void __launch_bounds__(256, 4)
kernRing(const float* __restrict__ x, const int* __restrict__ smask,
         const float* __restrict__ ns, const float* __restrict__ nb,
         const float* __restrict__ br, const float* __restrict__ brg,
         const u16* __restrict__ WTr, u16* __restrict__ ring, int k0)
{
  __shared__ u16 sWT[256 * 64];   // 32KB, swizzled image rows 0..255
  __shared__ u16 sA[64 * 64];     // 8KB, swizzled
  const int bid = blockIdx.x;
  const int slot = bid >> 3, tile = bid & 7;
  const int p = k0 + slot;
  if (p < 0 || p >= LL) return;
  const int t = threadIdx.x;
  const int lane = t & 63;
  const int wave = t >> 6;
  const int l15 = lane & 15, l4 = lane >> 4;
  const int q0 = tile * 64;

  { // stage Wr|Wrg: linear uint4 copy of pre-swizzled image
    const uint4* src = (const uint4*)WTr;
    uint4* dst = (uint4*)sWT;
#pragma unroll
    for (int c = 0; c < 8; ++c) dst[t + c * 256] = src[t + c * 256];
  }

  const float mrow = (float)smask[p];
  const int ql = t >> 2, qc = t & 3;      // pair-in-tile, dim-quarter
  float4 nsv[4], nbv[4];
#pragma unroll
  for (int j = 0; j < 4; j++) {
    nsv[j] = *(const float4*)(ns + qc * 16 + j * 4);
    nbv[j] = *(const float4*)(nb + qc * 16 + j * 4);
  }
  float brv[2], brgv[2];
#pragma unroll
  for (int fp = 0; fp < 2; fp++) {
    int h = wave * 32 + fp * 16 + l15;
    brv[fp] = br[h]; brgv[fp] = brg[h];
  }

  { // ---- LN -> sA (bf16, swizzled) — verified verbatim
    const int q = q0 + ql;
    const float* xp = x + ((size_t)p * LL + q) * DIMC + qc * 16;
    float4 xv[4];
    float s = 0.f, ss = 0.f;
#pragma unroll
    for (int j = 0; j < 4; j++) {
      xv[j] = *(const float4*)(xp + j * 4);
      s += xv[j].x + xv[j].y + xv[j].z + xv[j].w;
      ss += xv[j].x * xv[j].x + xv[j].y * xv[j].y + xv[j].z * xv[j].z + xv[j].w * xv[j].w;
    }
    s += __shfl_xor(s, 1); ss += __shfl_xor(ss, 1);
    s += __shfl_xor(s, 2); ss += __shfl_xor(ss, 2);
    const float mean = s * (1.f / 64.f);
    const float var = ss * (1.f / 64.f) - mean * mean;
    const float rstd = rsqrtf(var + 1e-6f);
    u16 xb[16];
#pragma unroll
    for (int j = 0; j < 4; j++) {
      xb[j*4+0] = f2bf((xv[j].x - mean) * rstd * nsv[j].x + nbv[j].x);
      xb[j*4+1] = f2bf((xv[j].y - mean) * rstd * nsv[j].y + nbv[j].y);
      xb[j*4+2] = f2bf((xv[j].z - mean) * rstd * nsv[j].z + nbv[j].z);
      xb[j*4+3] = f2bf((xv[j].w - mean) * rstd * nsv[j].w + nbv[j].w);
    }
    uint4 c0, c1;
    c0.x = (u32)xb[0]  | ((u32)xb[1]  << 16);
    c0.y = (u32)xb[2]  | ((u32)xb[3]  << 16);
    c0.z = (u32)xb[4]  | ((u32)xb[5]  << 16);
    c0.w = (u32)xb[6]  | ((u32)xb[7]  << 16);
    c1.x = (u32)xb[8]  | ((u32)xb[9]  << 16);
    c1.y = (u32)xb[10] | ((u32)xb[11] << 16);
    c1.z = (u32)xb[12] | ((u32)xb[13] << 16);
    c1.w = (u32)xb[14] | ((u32)xb[15] << 16);
    char* rowp = (char*)sA + ql * 128;
    *(uint4*)(rowp + (((qc * 2 + 0) ^ (ql & 7)) << 4)) = c0;
    *(uint4*)(rowp + (((qc * 2 + 1) ^ (ql & 7)) << 4)) = c1;
  }
  __syncthreads();
  // ---- MFMA: [64 pairs x 64k] @ [64k x 256n] (Wr|Wrg groups)
  f32x4 acc[4][4];
  f32x4 zero = {0.f, 0.f, 0.f, 0.f};
#pragma unroll
  for (int m = 0; m < 4; m++)
#pragma unroll
    for (int f = 0; f < 4; f++) acc[m][f] = zero;
#pragma unroll
  for (int ks = 0; ks < 2; ks++) {
    bf16x8 av[4];
#pragma unroll
    for (int m = 0; m < 4; m++) {
      int row = m * 16 + l15;
      int ch = (ks * 4 + l4) ^ (row & 7);
      av[m] = *(const bf16x8*)((const char*)sA + row * 128 + (ch << 4));
    }
#pragma unroll
    for (int f = 0; f < 4; f++) {
      int g = f >> 1, fp = f & 1;
      int n = g * 128 + wave * 32 + fp * 16 + l15;
      int ch = (ks * 4 + l4) ^ (n & 7);
      bf16x8 bv = *(const bf16x8*)((const char*)sWT + n * 128 + (ch << 4));
#pragma unroll
      for (int m = 0; m < 4; m++)
        acc[m][f] = __builtin_amdgcn_mfma_f32_16x16x32_bf16(av[m], bv, acc[m][f], 0, 0, 0);
    }
  }
  // ---- epilogue: bias, mask, sigmoid gate; scalar ring stores
#pragma unroll
  for (int m = 0; m < 4; m++) {
    float mvr[4];
#pragma unroll
    for (int r = 0; r < 4; r++)
      mvr[r] = mrow * (float)smask[q0 + m * 16 + l4 * 4 + r];
#pragma unroll
    for (int fp = 0; fp < 2; fp++) {
      const int h = wave * 32 + fp * 16 + l15;
      f32x4 lin = acc[m][fp];
      f32x4 gat = acc[m][2 + fp];
#pragma unroll
      for (int r = 0; r < 4; r++) {
        const int qq = q0 + m * 16 + l4 * 4 + r;
        ring[((size_t)slot * LL + qq) * HIDC + h] =
            f2bf((lin[r] + brv[fp]) * mvr[r] * sigm(gat[r] + brgv[fp]));
      }
    }
  }
}

// ---- kernel Og: LN + out-gate projection (r10 verbatim) -----------------
extern "C" __global__ void __launch_bounds__(256, 4)
kernOg(const float* __restrict__ x, const int* __restrict__ smask,
       const float* __restrict__ ns, const float* __restrict__ nb,
       const float* __restrict__ bog, const u16* __restrict__ WTr,
       u16* __restrict__ og, int i0)
{
  __shared__ u16 sWog[128 * 64];  // 16KB, swizzled image rows 256..383
  __shared__ u16 sA[64 * 64];     // 8KB, swizzled
  const int bid = blockIdx.x;
  const int p = i0 + (bid >> 3);
  const int tile = bid & 7;
  const int t = threadIdx.x;
  const int lane = t & 63;
  const int wave = t >> 6;
  const int l15 = lane & 15, l4 = lane >> 4;
  const int q0 = tile * 64;

  { // stage Wog: linear uint4 copy of image rows 256..383
    const uint4* src = (const uint4*)(WTr + 256 * 64);
    uint4* dst = (uint4*)sWog;
#pragma unroll
    for (int c = 0; c < 4; ++c) dst[t + c * 256] = src[t + c * 256];
  }

  const int ql = t >> 2, qc = t & 3;      // pair-in-tile, dim-quarter
  float4 nsv[4], nbv[4];
#pragma unroll
  for (int j = 0; j < 4; j++) {
    nsv[j] = *(const float4*)(ns + qc * 16 + j * 4);
    nbv[j] = *(const float4*)(nb + qc * 16 + j * 4);
  }
  float bogv[2];
#pragma unroll
  for (int fp = 0; fp < 2; fp++) bogv[fp] = bog[wave * 32 + fp * 16 + l15];

  { // ---- LN -> sA (bf16, swizzled) — verified verbatim
    const int q = q0 + ql;
    const float* xp = x + ((size_t)p * LL + q) * DIMC + qc * 16;
    float4 xv[4];
    float s = 0.f, ss = 0.f;
#pragma unroll
    for (int j = 0; j < 4; j++) {
      xv[j] = *(const float4*)(xp + j * 4);
      s += xv[j].x + xv[j].y + xv[j].z + xv[j].w;
      ss += xv[j].x * xv[j].x + xv[j].y * xv[j].y + xv[j].z * xv[j].z + xv[j].w * xv[j].w;
    }
    s += __shfl_xor(s, 1); ss += __shfl_xor(ss, 1);
    s += __shfl_xor(s, 2); ss += __shfl_xor(ss, 2);
    const float mean = s * (1.f / 64.f);
    const float rstd = rsqrtf(ss * (1.f / 64.f) - mean * mean + 1e-6f);
    u16 xb[16];
#pragma unroll
    for (int j = 0; j < 4; j++) {
      xb[j*4+0] = f2bf((xv[j].x - mean) * rstd * nsv[j].x + nbv[j].x);
      xb[j*4+1] = f2bf((xv[j].y - mean) * rstd * nsv[j].y + nbv[j].y);
      xb[j*4+2] = f2bf((xv[j].z - mean) * rstd * nsv[j].z + nbv[j].z);
      xb[j*4+3] = f2bf((xv[j].w - mean) * rstd * nsv[j].w + nbv[j].w);
    }
    uint4 c0, c1;
    c0.x = (u32)xb[0]  | ((u32)xb[1]  << 16);
    c0.y = (u32)xb[2]  | ((u32)xb[3]  << 16);
    c0.z = (u32)xb[4]  | ((u32)xb[5]  << 16);
    c0.w = (u32)xb[6]  | ((u32)xb[7]  << 16);
    c1.x = (u32)xb[8]  | ((u32)xb[9]  << 16);
    c1.y = (u32)xb[10] | ((u32)xb[11] << 16);
    c1.z = (u32)xb[12] | ((u32)xb[13] << 16);
    c1.w = (u32)xb[14] | ((u32)xb[15] << 16);
    char* rowp = (char*)sA + ql * 128;
    *(uint4*)(rowp + (((qc * 2 + 0) ^ (ql & 7)) << 4)) = c0;
    *(uint4*)(rowp + (((qc * 2 + 1) ^ (ql & 7)) << 4)) = c1;
  }
  __syncthreads();
  // ---- MFMA: [64 pairs x 64k] @ [64k x 128n] (Wog group)
  f32x4 acc[4][2];
  f32x4 zero = {0.f, 0.f, 0.f, 0.f};
#pragma unroll
  for (int m = 0; m < 4; m++) { acc[m][0] = zero; acc[m][1] = zero; }
#pragma unroll
  for (int ks = 0; ks < 2; ks++) {
    bf16x8 av[4];
#pragma unroll
    for (int m = 0; m < 4; m++) {
      int row = m * 16 + l15;
      int ch = (ks * 4 + l4) ^ (row & 7);
      av[m] = *(const bf16x8*)((const char*)sA + row * 128 + (ch << 4));
    }
#pragma unroll
    for (int fp = 0; fp < 2; fp++) {
      int n = wave * 32 + fp * 16 + l15;       // image row 256+n; (256+n)&7 == n&7
      int ch = (ks * 4 + l4) ^ (n & 7);
      bf16x8 bv = *(const bf16x8*)((const char*)sWog + n * 128 + (ch << 4));
#pragma unroll
      for (int m = 0; m < 4; m++)
        acc[m][fp] = __builtin_amdgcn_mfma_f32_16x16x32_bf16(av[m], bv, acc[m][fp], 0, 0, 0);
    }
  }
  // ---- epilogue: sigmoid; scalar og stores
#pragma unroll
  for (int m = 0; m < 4; m++)
#pragma unroll
    for (int fp = 0; fp < 2; fp++) {
      const int h = wave * 32 + fp * 16 + l15;
      f32x4 ogv = acc[m][fp];
#pragma unroll
      for (int r = 0; r < 4; r++) {
        const int qq = q0 + m * 16 + l4 * 4 + r;
        og[((size_t)p * LL + qq) * HIDC + h] = f2bf(sigm(ogv[r] + bogv[fp]));
      }
    }
}

// ---- kernel L: left on the 9 diagonals via MFMA (r10 verbatim) ----------
extern "C" __global__ void __launch_bounds__(256, 2)
kernL(const float* __restrict__ x, const int* __restrict__ smask,
      const float* __restrict__ ns, const float* __restrict__ nb,
      const float* __restrict__ bl, const float* __restrict__ blg,
      const u16* __restrict__ WTl, float* __restrict__ Lbuf)
{
  __shared__ u16 sW[256 * 64];    // 32KB swizzled image
  __shared__ u16 sA[64 * 64];     // 8KB swizzled LN'd rows
  const int g0 = blockIdx.x * 64;
  const int t = threadIdx.x;
  const int lane = t & 63, wave = t >> 6;
  const int l15 = lane & 15, l4 = lane >> 4;

  { // stage weights: linear uint4 copy of pre-swizzled image
    const uint4* src = (const uint4*)WTl;
    uint4* dst = (uint4*)sW;
#pragma unroll
    for (int c = 0; c < 8; ++c) dst[t + c * 256] = src[t + c * 256];
  }

  const int ql = t >> 2, qc = t & 3;     // row-in-tile, dim-quarter
  { // ---- LN -> sA: row g = g0+ql -> (i = g/9, d = g%9, p = i+d-4)
    const int g = g0 + ql;
    const int i = g / 9, d = g - 9 * i;
    int p = i + d - 4;
    p = (p < 0) ? 0 : (p > LL - 1 ? LL - 1 : p);   // clamp; invalid rows zeroed later
    const float* xp = x + ((size_t)p * LL + i) * DIMC + qc * 16;
    float4 xv[4];
    float s = 0.f, ss = 0.f;
#pragma unroll
    for (int j = 0; j < 4; j++) {
      xv[j] = *(const float4*)(xp + j * 4);
      s += xv[j].x + xv[j].y + xv[j].z + xv[j].w;
      ss += xv[j].x * xv[j].x + xv[j].y * xv[j].y + xv[j].z * xv[j].z + xv[j].w * xv[j].w;
    }
    s += __shfl_xor(s, 1); ss += __shfl_xor(ss, 1);
    s += __shfl_xor(s, 2); ss += __shfl_xor(ss, 2);
    const float mean = s * (1.f / 64.f);
    const float rstd = rsqrtf(ss * (1.f / 64.f) - mean * mean + 1e-6f);
    u16 xb[16];
#pragma unroll
    for (int j = 0; j < 4; j++) {
      const float4 nsv = *(const float4*)(ns + qc * 16 + j * 4);
      const float4 nbv = *(const float4*)(nb + qc * 16 + j * 4);
      xb[j*4+0] = f2bf((xv[j].x - mean) * rstd * nsv.x + nbv.x);
      xb[j*4+1] = f2bf((xv[j].y - mean) * rstd * nsv.y + nbv.y);
      xb[j*4+2] = f2bf((xv[j].z - mean) * rstd * nsv.z + nbv.z);
      xb[j*4+3] = f2bf((xv[j].w - mean) * rstd * nsv.w + nbv.w);
    }
    uint4 c0, c1;
    c0.x = (u32)xb[0]  | ((u32)xb[1]  << 16);
    c0.y = (u32)xb[2]  | ((u32)xb[3]  << 16);
    c0.z = (u32)xb[4]  | ((u32)xb[5]  << 16);
    c0.w = (u32)xb[6]  | ((u32)xb[7]  << 16);
    c1.x = (u32)xb[8]  | ((u32)xb[9]  << 16);
    c1.y = (u32)xb[10] | ((u32)xb[11] << 16);
    c1.z = (u32)xb[12] | ((u32)xb[13] << 16);
    c1.w = (u32)xb[14] | ((u32)xb[15] << 16);
    char* rowp = (char*)sA + ql * 128;
    *(uint4*)(rowp + (((qc * 2 + 0) ^ (ql & 7)) << 4)) = c0;
    *(uint4*)(rowp + (((qc * 2 + 1) ^ (ql & 7)) << 4)) = c1;
  }
  __syncthreads();
  // ---- MFMA: [64 rows x 64k] @ [64k x 256n]
  f32x4 acc[4][4];
  f32x4 zero = {0.f, 0.f, 0.f, 0.f};
#pragma unroll
  for (int m = 0; m < 4; m++)
#pragma unroll
    for (int f = 0; f < 4; f++) acc[m][f] = zero;
#pragma unroll
  for (int ks = 0; ks < 2; ks++) {
    bf16x8 av[4];
#pragma unroll
    for (int m = 0; m < 4; m++) {
      int row = m * 16 + l15;
      int ch = (ks * 4 + l4) ^ (row & 7);
      av[m] = *(const bf16x8*)((const char*)sA + row * 128 + (ch << 4));
    }
#pragma unroll
    for (int f = 0; f < 4; f++) {
      int grp = f >> 1, fp = f & 1;
      int n = grp * 128 + wave * 32 + fp * 16 + l15;
      int ch = (ks * 4 + l4) ^ (n & 7);
      bf16x8 bv = *(const bf16x8*)((const char*)sW + n * 128 + (ch << 4));
#pragma unroll
      for (int m = 0; m < 4; m++)
        acc[m][f] = __builtin_amdgcn_mfma_f32_16x16x32_bf16(av[m], bv, acc[m][f], 0, 0, 0);
    }
  }
  // ---- epilogue: (lin+bl)*mask*sigm(gate+blg) -> Lbuf f32
#pragma unroll
  for (int fp = 0; fp < 2; fp++) {
    const int h = wave * 32 + fp * 16 + l15;
    const float blv = bl[h], blgv = blg[h];
#pragma unroll
    for (int m = 0; m < 4; m++) {
      f32x4 lin = acc[m][fp];
      f32x4 gat = acc[m][2 + fp];
#pragma unroll
      for (int r = 0; r < 4; r++) {
        const int g = g0 + m * 16 + l4 * 4 + r;
        const int i = g / 9, d = g - 9 * i;
        const int p = i + d - 4;
        const bool valid = (p >= 0) && (p < LL);
        const float mv = valid ? (float)smask[i] * (float)smask[valid ? p : 0] : 0.f;
        Lbuf[(size_t)g * HIDC + h] = (lin[r] + blv) * mv * sigm(gat[r] + blgv);
      }
    }
  }
}

// ---- kernel B: banded product + LN + gate + Wo proj (r10 verbatim) ------
// og aliases d_out; each block reads only its own (i, j-tile) og rows and
// overwrites exactly those rows with the final output (ordered by barrier).
extern "C" __global__ void __launch_bounds__(256, 4)
kernB(const u16* __restrict__ ring, const u16* og,
      const float* __restrict__ Lbuf, const u16* __restrict__ WoT,
      const float* __restrict__ osc, const float* __restrict__ obi,
      const float* __restrict__ bo, float* out, int k0, int i0)
{
  __shared__ u16 sWo[64 * 128];   // 16KB swizzled image
  __shared__ u16 sA[64 * 128];    // 16KB swizzled
  __shared__ float sLb[9 * 128];
  const int bid = blockIdx.x;
  const int i = i0 + (bid >> 3), j0 = (bid & 7) * 64;
  const int t = threadIdx.x;
  const int lane = t & 63, wave = t >> 6;
  const int l15 = lane & 15, l4 = lane >> 4;
  { // stage Wo: linear uint4 copy of pre-swizzled image
    const uint4* src = (const uint4*)WoT;
    uint4* dst = (uint4*)sWo;
#pragma unroll
    for (int c = 0; c < 4; ++c) dst[t + c * 256] = src[t + c * 256];
    const float* lb = Lbuf + (size_t)i * (9 * HIDC);
    for (int idx = t; idx < 9 * HIDC; idx += 256) sLb[idx] = lb[idx];
  }
  __syncthreads();
  const int j = t >> 2, hq = t & 3, h0 = hq * 32;
  float acc[32];
#pragma unroll
  for (int e = 0; e < 32; e++) acc[e] = 0.f;
  for (int d = 0; d < 9; d++) {
    const int k = i + d - 4;
    if (k < 0 || k >= LL) continue;
    const int slot = k - k0;
    const u16* rp = ring + ((size_t)slot * LL + j0 + j) * HIDC + h0;
#pragma unroll
    for (int c4 = 0; c4 < 4; c4++) {
      uint4 rv = *(const uint4*)(rp + c4 * 8);
      const float4 lb0 = *(const float4*)(sLb + d * 128 + h0 + c4 * 8);
      const float4 lb1 = *(const float4*)(sLb + d * 128 + h0 + c4 * 8 + 4);
      acc[c4*8+0] = fmaf(lb0.x, bf2f(rv.x & 0xffff), acc[c4*8+0]);
      acc[c4*8+1] = fmaf(lb0.y, bf2f(rv.x >> 16),    acc[c4*8+1]);
      acc[c4*8+2] = fmaf(lb0.z, bf2f(rv.y & 0xffff), acc[c4*8+2]);
      acc[c4*8+3] = fmaf(lb0.w, bf2f(rv.y >> 16),    acc[c4*8+3]);
      acc[c4*8+4] = fmaf(lb1.x, bf2f(rv.z & 0xffff), acc[c4*8+4]);
      acc[c4*8+5] = fmaf(lb1.y, bf2f(rv.z >> 16),    acc[c4*8+5]);
      acc[c4*8+6] = fmaf(lb1.z, bf2f(rv.w & 0xffff), acc[c4*8+6]);
      acc[c4*8+7] = fmaf(lb1.w, bf2f(rv.w >> 16),    acc[c4*8+7]);
    }
  }
  // LN over 128 (4 threads per j)
  float s = 0.f, ss = 0.f;
#pragma unroll
  for (int e = 0; e < 32; e++) { s += acc[e]; ss += acc[e] * acc[e]; }
  s += __shfl_xor(s, 1); ss += __shfl_xor(ss, 1);
  s += __shfl_xor(s, 2); ss += __shfl_xor(ss, 2);
  const float mean = s * (1.f / 128.f);
  const float rstd = rsqrtf(ss * (1.f / 128.f) - mean * mean + 1e-6f);
  const u16* ogp = og + ((size_t)i * LL + j0 + j) * HIDC + h0;
  char* rowp = (char*)sA + j * 256;
#pragma unroll
  for (int c4 = 0; c4 < 4; c4++) {
    const float4 o0 = *(const float4*)(osc + h0 + c4 * 8);
    const float4 o1 = *(const float4*)(osc + h0 + c4 * 8 + 4);
    const float4 b0 = *(const float4*)(obi + h0 + c4 * 8);
    const float4 b1 = *(const float4*)(obi + h0 + c4 * 8 + 4);
    uint4 gv = *(const uint4*)(ogp + c4 * 8);
    float v0 = ((acc[c4*8+0] - mean) * rstd * o0.x + b0.x) * bf2f(gv.x & 0xffff);
    float v1 = ((acc[c4*8+1] - mean) * rstd * o0.y + b0.y) * bf2f(gv.x >> 16);
    float v2 = ((acc[c4*8+2] - mean) * rstd * o0.z + b0.z) * bf2f(gv.y & 0xffff);
    float v3 = ((acc[c4*8+3] - mean) * rstd * o0.w + b0.w) * bf2f(gv.y >> 16);
    float v4 = ((acc[c4*8+4] - mean) * rstd * o1.x + b1.x) * bf2f(gv.z & 0xffff);
    float v5 = ((acc[c4*8+5] - mean) * rstd * o1.y + b1.y) * bf2f(gv.z >> 16);
    float v6 = ((acc[c4*8+6] - mean) * rstd * o1.z + b1.z) * bf2f(gv.w & 0xffff);
    float v7 = ((acc[c4*8+7] - mean) * rstd * o1.w + b1.w) * bf2f(gv.w >> 16);
    uint4 pk;
    pk.x = (u32)f2bf(v0) | ((u32)f2bf(v1) << 16);
    pk.y = (u32)f2bf(v2) | ((u32)f2bf(v3) << 16);
    pk.z = (u32)f2bf(v4) | ((u32)f2bf(v5) << 16);
    pk.w = (u32)f2bf(v6) | ((u32)f2bf(v7) << 16);
    *(uint4*)(rowp + (((hq * 4 + c4) ^ (j & 7)) << 4)) = pk;
  }
  __syncthreads();   // og fully read; sA ready
  f32x4 acc2[4];
  f32x4 zero = {0.f, 0.f, 0.f, 0.f};
#pragma unroll
  for (int m = 0; m < 4; m++) acc2[m] = zero;
#pragma unroll
  for (int ks = 0; ks < 4; ks++) {
    int n = wave * 16 + l15;
    int chb = (ks * 4 + l4) ^ (n & 7);
    bf16x8 bv = *(const bf16x8*)((const char*)sWo + n * 256 + (chb << 4));
#pragma unroll
    for (int m = 0; m < 4; m++) {
      int row = m * 16 + l15;
      int cha = (ks * 4 + l4) ^ (row & 7);
      bf16x8 av = *(const bf16x8*)((const char*)sA + row * 256 + (cha << 4));
      acc2[m] = __builtin_amdgcn_mfma_f32_16x16x32_bf16(av, bv, acc2[m], 0, 0, 0);
    }
  }
  const int dim = wave * 16 + l15;
  const float bov = bo[dim];
#pragma unroll
  for (int m = 0; m < 4; m++) {
#pragma unroll
    for (int r = 0; r < 4; r++) {
      int jj = j0 + m * 16 + l4 * 4 + r;
      out[((size_t)i * LL + jj) * DIMC + dim] = acc2[m][r] + bov;
    }
  }
}

extern "C" void kernel_launch(void* const* d_in, const int* in_sizes, int n_in,
                              void* d_out, int out_size, void* d_ws, size_t ws_size,
                              hipStream_t stream) {
  const float* x    = (const float*)d_in[0];
  const int*   sm   = (const int*)d_in[1];
  const float* ns   = (const float*)d_in[2];
  const float* nb   = (const float*)d_in[3];
  const float* Wl   = (const float*)d_in[4];
  const float* bl   = (const float*)d_in[5];
  const float* Wr   = (const float*)d_in[6];
  const float* br   = (const float*)d_in[7];
  const float* Wlg  = (const float*)d_in[8];
  const float* blg  = (const float*)d_in[9];
  const float* Wrg  = (const float*)d_in[10];
  const float* brg  = (const float*)d_in[11];
  const float* Wog  = (const float*)d_in[12];
  const float* bog  = (const float*)d_in[13];
  const float* osc  = (const float*)d_in[14];
  const float* obi  = (const float*)d_in[15];
  const float* Wo   = (const float*)d_in[16];
  const float* bo   = (const float*)d_in[17];

  // ws layout: Lbuf f32 | WTr 48KB | WTl 32KB | WoT 16KB | ring.
  const size_t LBUF_BYTES = (size_t)LL * 9 * HIDC * 4;   // 2,359,296
  char* ws = (char*)d_ws;
  float* Lbuf = (float*)ws;
  u16* WTr = (u16*)(ws + LBUF_BYTES);
  u16* WTl = (u16*)(ws + LBUF_BYTES + 49152);
  u16* WoT = (u16*)(ws + LBUF_BYTES + 49152 + 32768);
  u16* ring = (u16*)(ws + LBUF_BYTES + 49152 + 32768 + 16384);

  int CHUNK = 256;
  if (ws_size < LBUF_BYTES + 98304 + (size_t)(256 + 8) * LL * HIDC * 2) CHUNK = 64;
  u16* ogB = (u16*)d_out;   // og lives in d_out, chunk-local, consumed by kernB

  prep<<<32, 256, 0, stream>>>(Wr, Wrg, Wog, Wl, Wlg, Wo, WTr, WTl, WoT);
  kernL<<<72, 256, 0, stream>>>(x, sm, ns, nb, bl, blg, WTl, Lbuf);
  for (int i0 = 0; i0 < LL; i0 += CHUNK) {
    const int k0 = i0 - 4;
    // LAW 2: kernB must IMMEDIATELY follow kernRing (its 33.8MB ring input
    // falls out of L2 if another launch intervenes: 18us -> 48us).
    kernOg<<<CHUNK * 8, 256, 0, stream>>>(x, sm, ns, nb, bog, WTr, ogB, i0);
    kernRing<<<(CHUNK + 8) * 8, 256, 0, stream>>>(x, sm, ns, nb, br, brg, WTr, ring, k0);
    kernB<<<CHUNK * 8, 256, 0, stream>>>(ring, ogB, Lbuf, WoT, osc, obi, bo,
                                         (float*)d_out, k0, i0);
  }
}